// Round 6
// baseline (75.520 us; speedup 1.0000x reference)
//
#include <hip/hip_runtime.h>
#include <hip/hip_bf16.h>

#define NQ     8
#define SEQL   128
#define BATCHN 256
#define EMBED  512
#define DIN    520          // EMBED + NQ
#define NROWS  (SEQL*BATCHN) // 32768
#define GSTR   32           // 4 gates * 8 qubits
#define INV2PI 0.15915494309189535f
#define ROWSB  128          // k1 rows per block
#define KC     64           // k1 K-chunk

// ---------------------------------------------------------------------------
// DPP helpers: row_shr:N -> lane i gets i-N ; row_shl:N -> i+N ; row_ror:N
// ---------------------------------------------------------------------------
#define DPP_QP(a,b,c,d) ((a)|((b)<<2)|((c)<<4)|((d)<<6))
#define DPP_SHL(n) (0x100+(n))
#define DPP_SHR(n) (0x110+(n))
#define DPP_ROR(n) (0x120+(n))

template<int CTRL>
__device__ __forceinline__ float updpf(float old_, float src) {
    return __int_as_float(__builtin_amdgcn_update_dpp(
        __float_as_int(old_), __float_as_int(src), CTRL, 0xF, 0xF, false));
}

typedef unsigned int uint2v __attribute__((ext_vector_type(2)));
// value of x at lane^32, semantics-proof: permlane32_swap returns the
// {vdst,vsrc} pair; per lane exactly one element is own x, the other is
// x[lane^32]; bitwise a^b^x extracts the partner either way.
__device__ __forceinline__ float xor32f(float x) {
    unsigned xu = (unsigned)__float_as_int(x);
    uint2v r = __builtin_amdgcn_permlane32_swap(xu, xu, false, false);
    return __int_as_float((int)(r.x ^ r.y ^ xu));
}

__device__ __forceinline__ float frcp(float x) { return __builtin_amdgcn_rcpf(x); }

// Pade(5,4) tanh — |z| <= 1 : err < 2e-7
__device__ __forceinline__ float tanh54(float z) {
    float w = z * z;
    float nu = fmaf(fmaf(1.0f, w, 105.f), w, 945.f) * z;
    float de = fmaf(fmaf(15.f, w, 420.f), w, 945.f);
    return nu * frcp(de);
}
// Pade(7,6) tanh — |z| <= 2.2 : err < 5e-5
__device__ __forceinline__ float tanh76(float z) {
    float w = z * z;
    float nu = fmaf(fmaf(fmaf(1.f, w, 378.f), w, 17325.f), w, 135135.f) * z;
    float de = fmaf(fmaf(fmaf(28.f, w, 3150.f), w, 62370.f), w, 135135.f);
    return nu * frcp(de);
}

// ---------------------------------------------------------------------------
// Kernel 1: G[row*32+c] = (emb[sent[row]].W_c + b_c + th_c) * INV2PI
//   128-row x 32-col tile per block (256 blocks), 4x4 outputs/thread.
//   X staged TRANSPOSED (Xs[k][row]) -> inner loop = 2 ds_read_b128 / 16 FMA,
//   both conflict-free. Next chunk's globals prefetched to regs (T14 split).
// ---------------------------------------------------------------------------
__global__ __launch_bounds__(256, 2)
void k1_gates(const int* __restrict__ sent, const float* __restrict__ emb,
              const float* __restrict__ Wf, const float* __restrict__ Wi,
              const float* __restrict__ Wu, const float* __restrict__ Wo,
              const float* __restrict__ bf, const float* __restrict__ bi,
              const float* __restrict__ bu, const float* __restrict__ bo,
              const float* __restrict__ thf, const float* __restrict__ thi,
              const float* __restrict__ thu, const float* __restrict__ tho,
              float* __restrict__ G)
{
    __shared__ float Xs[KC][ROWSB + 1];   // 33 KB, transposed [k][row]
    __shared__ float Ws[KC][36];          // 9.2 KB, [k][col]
    __shared__ int   tok[ROWSB];

    const int tid  = threadIdx.x;
    const int row0 = blockIdx.x * ROWSB;
    if (tid < ROWSB) tok[tid] = sent[row0 + tid];

    const int rg = tid >> 3;   // 0..31 -> rows rg*4 .. rg*4+3
    const int cg = tid & 7;    // 0..7  -> cols cg*4 .. cg*4+3

    float acc[4][4] = {};
    __syncthreads();

    // ---- stage chunk 0 directly ----
    #pragma unroll
    for (int i = 0; i < 8; ++i) {
        int f4 = tid + i * 256;
        int r  = f4 >> 4, kq = f4 & 15;
        float4 v = *reinterpret_cast<const float4*>(
            &emb[(size_t)tok[r] * EMBED + kq * 4]);
        Xs[kq*4+0][r] = v.x; Xs[kq*4+1][r] = v.y;
        Xs[kq*4+2][r] = v.z; Xs[kq*4+3][r] = v.w;
    }
    #pragma unroll
    for (int i = 0; i < 8; ++i) {
        int idx = tid + i * 256;
        int c   = idx >> 6, kk = idx & 63;
        int g = c >> 3, j = c & 7;
        const float* W = (g == 0) ? Wf : (g == 1) ? Wi : (g == 2) ? Wu : Wo;
        Ws[kk][c] = W[j * DIN + kk];
    }
    __syncthreads();

    float4 xn[8];
    float  wn[8];
    #pragma unroll 1
    for (int ch = 0; ch < 8; ++ch) {
        const int k0n = (ch + 1) * KC;
        if (ch < 7) {
            // prefetch next chunk to registers (latency hides under compute)
            #pragma unroll
            for (int i = 0; i < 8; ++i) {
                int f4 = tid + i * 256;
                int r  = f4 >> 4, kq = f4 & 15;
                xn[i] = *reinterpret_cast<const float4*>(
                    &emb[(size_t)tok[r] * EMBED + k0n + kq * 4]);
            }
            #pragma unroll
            for (int i = 0; i < 8; ++i) {
                int idx = tid + i * 256;
                int c   = idx >> 6, kk = idx & 63;
                int g = c >> 3, j = c & 7;
                const float* W = (g == 0) ? Wf : (g == 1) ? Wi : (g == 2) ? Wu : Wo;
                wn[i] = W[j * DIN + k0n + kk];
            }
        }
        #pragma unroll 16
        for (int kk = 0; kk < KC; ++kk) {
            float4 xv = *reinterpret_cast<const float4*>(&Xs[kk][rg * 4]);
            float4 wv = *reinterpret_cast<const float4*>(&Ws[kk][cg * 4]);
            acc[0][0]+=xv.x*wv.x; acc[0][1]+=xv.x*wv.y; acc[0][2]+=xv.x*wv.z; acc[0][3]+=xv.x*wv.w;
            acc[1][0]+=xv.y*wv.x; acc[1][1]+=xv.y*wv.y; acc[1][2]+=xv.y*wv.z; acc[1][3]+=xv.y*wv.w;
            acc[2][0]+=xv.z*wv.x; acc[2][1]+=xv.z*wv.y; acc[2][2]+=xv.z*wv.z; acc[2][3]+=xv.z*wv.w;
            acc[3][0]+=xv.w*wv.x; acc[3][1]+=xv.w*wv.y; acc[3][2]+=xv.w*wv.z; acc[3][3]+=xv.w*wv.w;
        }
        __syncthreads();
        if (ch < 7) {
            #pragma unroll
            for (int i = 0; i < 8; ++i) {
                int f4 = tid + i * 256;
                int r  = f4 >> 4, kq = f4 & 15;
                Xs[kq*4+0][r] = xn[i].x; Xs[kq*4+1][r] = xn[i].y;
                Xs[kq*4+2][r] = xn[i].z; Xs[kq*4+3][r] = xn[i].w;
            }
            #pragma unroll
            for (int i = 0; i < 8; ++i) {
                int idx = tid + i * 256;
                int c   = idx >> 6, kk = idx & 63;
                Ws[kk][c] = wn[i];
            }
            __syncthreads();
        }
    }

    // epilogue: (b + theta) * INV2PI folded; outputs in revolutions
    const int   gq = cg >> 1;
    const float* B  = (gq == 0) ? bf  : (gq == 1) ? bi  : (gq == 2) ? bu  : bo;
    const float* Th = (gq == 0) ? thf : (gq == 1) ? thi : (gq == 2) ? thu : tho;
    float bc[4];
    #pragma unroll
    for (int n = 0; n < 4; ++n)
        bc[n] = (B[(cg&1)*4+n] + Th[(cg&1)*4+n]) * INV2PI;

    #pragma unroll
    for (int rr = 0; rr < 4; ++rr) {
        float4 o = make_float4(fmaf(acc[rr][0],INV2PI,bc[0]),
                               fmaf(acc[rr][1],INV2PI,bc[1]),
                               fmaf(acc[rr][2],INV2PI,bc[2]),
                               fmaf(acc[rr][3],INV2PI,bc[3]));
        size_t base = (size_t)(row0 + rg*4 + rr) * GSTR + cg*4;
        *reinterpret_cast<float4*>(&G[base]) = o;
    }
}

// ---------------------------------------------------------------------------
// Kernel 2: LSTM recurrence, closed-form qlayer, ALL-VALU cross-lane.
//   lane = g0<<5 | r<<4 | g1<<3 | j ; gate = 2*g0+g1 (f,i,u,o = 00,01,10,11).
//   j-group ops (scan/butterfly/H-gather): DPP within 16-lane rows.
//   gate gather: g1-flip = row_ror:8 (DPP), g0-flip = permlane32_swap (VALU).
//   No LDS in the loop except the prefetched gs read.
// ---------------------------------------------------------------------------
__global__ __launch_bounds__(64)
void k2_lstm(const float* __restrict__ G,
             const float* __restrict__ Wf, const float* __restrict__ Wi,
             const float* __restrict__ Wu, const float* __restrict__ Wo,
             float* __restrict__ out)
{
    __shared__ float gs[SEQL * 64];       // 32 KB: [t][r*32 + gate*8 + j]

    const int tid = threadIdx.x;          // 0..63, 1 wave
    const int j   = tid & 7;
    const int g1  = (tid >> 3) & 1;
    const int r   = (tid >> 4) & 1;
    const int g0  = tid >> 5;
    const int gate = g0 * 2 + g1;         // 0=f 1=i 2=u 3=o
    const int b   = blockIdx.x * 2 + r;
    const int gidx = r * 32 + gate * 8 + j;

    // ---- bulk stage this block's G timeline (128 t x 2 rows x 32 f32) ----
    {
        const float* gsrc = G + (size_t)blockIdx.x * 64;
        #pragma unroll 4
        for (int i = 0; i < 32; ++i) {
            int sl = i * 64 + tid;        // float4 slot 0..2047
            int st = sl >> 4, pc = sl & 15;
            float4 v = *reinterpret_cast<const float4*>(
                gsrc + (size_t)st * (BATCHN * GSTR) + pc * 4);
            *reinterpret_cast<float4*>(&gs[sl * 4]) = v;
        }
    }
    __syncthreads();

    const float* Wsel = (gate==0) ? Wf : (gate==1) ? Wi : (gate==2) ? Wu : Wo;

    // permuted, pre-scaled h-weights: dot = sum_r H[r]*Whp[r], H[r]=h[j^r]
    float Whp[8];
    #pragma unroll
    for (int rr = 0; rr < 8; ++rr)
        Whp[rr] = Wsel[j * DIN + EMBED + (j ^ rr)] * INV2PI;

    float H[8];
    #pragma unroll
    for (int rr = 0; rr < 8; ++rr) H[rr] = 0.f;
    float c_own = 0.f, h_own = 0.f;

    const float* gp = gs + gidx;
    float n = gp[0];

    const bool m1 = (j >= 1), m2 = (j >= 2), m4 = (j >= 4), jz = (j == 0);
    const bool bg0 = (g0 == 1), bg1 = (g1 == 1);
    // activation constants: u -> tanh(qv); f,i,o -> 0.5 + 0.5*tanh(qv/2)
    const float sc1 = (gate == 2) ? 1.0f : 0.5f;
    const float sc2 = (gate == 2) ? 1.0f : 0.5f;
    const float ofs = (gate == 2) ? 0.0f : 0.5f;

    for (int t = 0; t < SEQL; ++t) {
        // prefetch next step's value from LDS (off the dependence chain)
        float nn = gp[((t + 1 < SEQL) ? t + 1 : t) * 64];

        // a (revolutions) = G + h-dot (split 2x4 chains)
        float sA = fmaf(H[0], Whp[0], fmaf(H[1], Whp[1],
                    fmaf(H[2], Whp[2], H[3] * Whp[3])));
        float sB = fmaf(H[4], Whp[4], fmaf(H[5], Whp[5],
                    fmaf(H[6], Whp[6], H[7] * Whp[7])));
        float cs = __builtin_amdgcn_cosf(n + sA + sB);

        // inclusive prefix product over qubit group (row_shr, guarded)
        float p = cs, s;
        s = updpf<DPP_SHR(1)>(1.0f, p); p *= (m1 ? s : 1.0f);
        s = updpf<DPP_SHR(2)>(1.0f, p); p *= (m2 ? s : 1.0f);
        s = updpf<DPP_SHR(4)>(1.0f, p); p *= (m4 ? s : 1.0f);
        // product of cs_1..cs_7 (butterfly; lane j=0 contributes 1)
        float v = jz ? 1.0f : cs;
        v *= updpf<DPP_QP(1,0,3,2)>(v, v);
        v *= updpf<DPP_QP(2,3,0,1)>(v, v);
        float xl = updpf<DPP_SHL(4)>(v, v);
        float xr = updpf<DPP_SHR(4)>(v, v);
        v *= (m4 ? xr : xl);
        float qv = jz ? v : p;

        // activation (branchless, per-lane constants)
        float act = fmaf(sc2, tanh54(sc1 * qv), ofs);

        // gate gather, all-VALU:
        //   A own, B = g1-flip (ror8 in-row), C = g0-flip (lane^32), D = both
        float A = act;
        float Bv = updpf<DPP_ROR(8)>(A, A);
        float C  = xor32f(A);
        float D  = updpf<DPP_ROR(8)>(C, C);
        float E0 = bg1 ? Bv : A;    // gateval(g0, 0)
        float E1 = bg1 ? A  : Bv;   // gateval(g0, 1)
        float F0 = bg1 ? D  : C;    // gateval(!g0, 0)
        float F1 = bg1 ? C  : D;    // gateval(!g0, 1)
        float fv = bg0 ? F0 : E0;
        float iv = bg0 ? F1 : E1;
        float uv = bg0 ? E0 : F0;
        float ov = bg0 ? E1 : F1;

        c_own = fmaf(fv, c_own, iv * uv); // |c| <= 2.07
        h_own = ov * tanh76(c_own);

        // all-gather h across the 8-lane qubit group: H[r] = h[j^r]
        H[0] = h_own;
        H[1] = updpf<DPP_QP(1,0,3,2)>(H[0], H[0]);
        H[2] = updpf<DPP_QP(2,3,0,1)>(H[0], H[0]);
        H[3] = updpf<DPP_QP(2,3,0,1)>(H[1], H[1]);
        #pragma unroll
        for (int rr = 0; rr < 4; ++rr) {
            float yl = updpf<DPP_SHL(4)>(H[rr], H[rr]);
            float yr = updpf<DPP_SHR(4)>(H[rr], H[rr]);
            H[4 + rr] = m4 ? yr : yl;
        }

        n = nn;
    }

    if (!(tid & 0x28)) out[b * NQ + j] = h_own;   // one lane per (r,j): g0=g1=0
}

// ---------------------------------------------------------------------------
extern "C" void kernel_launch(void* const* d_in, const int* in_sizes, int n_in,
                              void* d_out, int out_size, void* d_ws, size_t ws_size,
                              hipStream_t stream)
{
    const int*   sent = (const int*)  d_in[0];
    // d_in[1] = features : unused by the reference
    const float* emb  = (const float*)d_in[2];
    const float* Wf   = (const float*)d_in[3];
    const float* bf   = (const float*)d_in[4];
    const float* Wi   = (const float*)d_in[5];
    const float* bi   = (const float*)d_in[6];
    const float* Wu   = (const float*)d_in[7];
    const float* bu   = (const float*)d_in[8];
    const float* Wo   = (const float*)d_in[9];
    const float* bo   = (const float*)d_in[10];
    const float* thf  = (const float*)d_in[11];
    const float* thi  = (const float*)d_in[12];
    const float* thu  = (const float*)d_in[13];
    const float* tho  = (const float*)d_in[14];
    float* out = (float*)d_out;

    float* G = (float*)d_ws;   // 32768 * 32 * 4B = 4 MB

    k1_gates<<<NROWS/ROWSB, 256, 0, stream>>>(sent, emb, Wf, Wi, Wu, Wo,
                                              bf, bi, bu, bo,
                                              thf, thi, thu, tho, G);
    k2_lstm<<<BATCHN/2, 64, 0, stream>>>(G, Wf, Wi, Wu, Wo, out);
}

// Round 7
// 53.010 us; speedup vs baseline: 1.4246x; 1.4246x over previous
//
#include <hip/hip_runtime.h>
#include <hip/hip_bf16.h>

#define NQ     8
#define SEQL   128
#define BATCHN 256
#define EMBED  512
#define DIN    520          // EMBED + NQ
#define NROWS  (SEQL*BATCHN) // 32768
#define GSTR   32           // 4 gates * 8 qubits
#define INV2PI 0.15915494309189535f

typedef __attribute__((ext_vector_type(8))) short  bf16x8;
typedef __attribute__((ext_vector_type(4))) float  f32x4;

__device__ __forceinline__ short f2bf(float f) {
    union { __hip_bfloat16 h; short s; } u;
    u.h = __float2bfloat16(f);          // RNE convert
    return u.s;
}

// ---------------------------------------------------------------------------
// DPP helpers: row_shr:N -> lane i gets i-N ; row_shl:N -> i+N
// ---------------------------------------------------------------------------
#define DPP_QP(a,b,c,d) ((a)|((b)<<2)|((c)<<4)|((d)<<6))
#define DPP_SHL(n) (0x100+(n))
#define DPP_SHR(n) (0x110+(n))

template<int CTRL>
__device__ __forceinline__ float updpf(float old_, float src) {
    return __int_as_float(__builtin_amdgcn_update_dpp(
        __float_as_int(old_), __float_as_int(src), CTRL, 0xF, 0xF, false));
}
// ds_swizzle BitMode: dst lane i reads ((i & and) | or) per 32 lanes
template<int OFF>
__device__ __forceinline__ float swzf(float x) {
    return __int_as_float(__builtin_amdgcn_ds_swizzle(__float_as_int(x), OFF));
}

__device__ __forceinline__ float frcp(float x) { return __builtin_amdgcn_rcpf(x); }

// Pade(5,4) tanh — |z| <= 1 : err < 2e-7
__device__ __forceinline__ float tanh54(float z) {
    float w = z * z;
    float nu = fmaf(fmaf(1.0f, w, 105.f), w, 945.f) * z;
    float de = fmaf(fmaf(15.f, w, 420.f), w, 945.f);
    return nu * frcp(de);
}
// Pade(7,6) tanh — |z| <= 2.2 : err < 5e-5
__device__ __forceinline__ float tanh76(float z) {
    float w = z * z;
    float nu = fmaf(fmaf(fmaf(1.f, w, 378.f), w, 17325.f), w, 135135.f) * z;
    float de = fmaf(fmaf(fmaf(28.f, w, 3150.f), w, 62370.f), w, 135135.f);
    return nu * frcp(de);
}

// ---------------------------------------------------------------------------
// Kernel 1 (MFMA): G[row*32+c] = (emb[sent[row]].W_c + b_c + th_c) * INV2PI
//   Block: 256 thr = 4 waves, M=64 rows. Wave w owns rows w*16..w*16+15,
//   N = 32 (2 x 16-col MFMA tiles), K = 512 in 16 steps of 32.
//   A: LDS bf16 [64][520] (row-pad 8 -> 2-way banks). B: global W, cvt in-loop
//   (L1-hot). Fragments: A/B = 8 consecutive bf16 per lane from [row][k]
//   row-major (m97 gemm_bt pattern); C: col=lane&15, row=4*(lane>>4)+reg.
// ---------------------------------------------------------------------------
__global__ __launch_bounds__(256, 2)
void k1_gates(const int* __restrict__ sent, const float* __restrict__ emb,
              const float* __restrict__ Wf, const float* __restrict__ Wi,
              const float* __restrict__ Wu, const float* __restrict__ Wo,
              const float* __restrict__ bf, const float* __restrict__ bi,
              const float* __restrict__ bu, const float* __restrict__ bo,
              const float* __restrict__ thf, const float* __restrict__ thi,
              const float* __restrict__ thu, const float* __restrict__ tho,
              float* __restrict__ G)
{
    __shared__ short Xs[64][520];       // 66.6 KB bf16, rows padded
    __shared__ int   tok[64];

    const int tid  = threadIdx.x;
    const int row0 = blockIdx.x * 64;
    if (tid < 64) tok[tid] = sent[row0 + tid];
    __syncthreads();

    // ---- stage X: 64 rows x 512 f32 -> bf16 LDS. 16 chunks of 8 per thread.
    #pragma unroll
    for (int p = 0; p < 16; ++p) {
        int flat8 = tid + p * 256;       // 0..4095 : (row, k8)
        int r  = flat8 >> 6;
        int k8 = flat8 & 63;
        const float* src = &emb[(size_t)tok[r] * EMBED + k8 * 8];
        float4 u = *reinterpret_cast<const float4*>(src);
        float4 v = *reinterpret_cast<const float4*>(src + 4);
        bf16x8 pk;
        pk[0]=f2bf(u.x); pk[1]=f2bf(u.y); pk[2]=f2bf(u.z); pk[3]=f2bf(u.w);
        pk[4]=f2bf(v.x); pk[5]=f2bf(v.y); pk[6]=f2bf(v.z); pk[7]=f2bf(v.w);
        *reinterpret_cast<bf16x8*>(&Xs[r][k8 * 8]) = pk;
    }
    __syncthreads();

    const int l   = tid & 63;            // lane
    const int w   = tid >> 6;            // wave -> M-tile
    const int lm  = l & 15;              // row-in-tile / col-in-tile
    const int q   = l >> 4;              // k-quarter (8 elems)

    // per-lane B row pointers + bias for the two N-tiles (c = n*16 + lm)
    const float* wrow[2];
    float bc[2];
    #pragma unroll
    for (int n = 0; n < 2; ++n) {
        int c = n * 16 + lm;
        int g = c >> 3, j = c & 7;
        const float* W  = (g==0) ? Wf  : (g==1) ? Wi  : (g==2) ? Wu  : Wo;
        const float* B  = (g==0) ? bf  : (g==1) ? bi  : (g==2) ? bu  : bo;
        const float* Th = (g==0) ? thf : (g==1) ? thi : (g==2) ? thu : tho;
        wrow[n] = W + (size_t)j * DIN;
        bc[n]   = (B[j] + Th[j]) * INV2PI;
    }

    f32x4 acc0 = {0.f,0.f,0.f,0.f};
    f32x4 acc1 = {0.f,0.f,0.f,0.f};
    const short* arow = &Xs[w * 16 + lm][0];

    #pragma unroll
    for (int kc = 0; kc < 16; ++kc) {
        const int kl = kc * 32 + q * 8;  // this lane's 8-elem k-chunk
        bf16x8 a = *reinterpret_cast<const bf16x8*>(&arow[kl]);
        // B fragments from global (L1-hot after first block)
        float4 u0 = *reinterpret_cast<const float4*>(wrow[0] + kl);
        float4 v0 = *reinterpret_cast<const float4*>(wrow[0] + kl + 4);
        float4 u1 = *reinterpret_cast<const float4*>(wrow[1] + kl);
        float4 v1 = *reinterpret_cast<const float4*>(wrow[1] + kl + 4);
        bf16x8 b0, b1;
        b0[0]=f2bf(u0.x); b0[1]=f2bf(u0.y); b0[2]=f2bf(u0.z); b0[3]=f2bf(u0.w);
        b0[4]=f2bf(v0.x); b0[5]=f2bf(v0.y); b0[6]=f2bf(v0.z); b0[7]=f2bf(v0.w);
        b1[0]=f2bf(u1.x); b1[1]=f2bf(u1.y); b1[2]=f2bf(u1.z); b1[3]=f2bf(u1.w);
        b1[4]=f2bf(v1.x); b1[5]=f2bf(v1.y); b1[6]=f2bf(v1.z); b1[7]=f2bf(v1.w);
        acc0 = __builtin_amdgcn_mfma_f32_16x16x32_bf16(a, b0, acc0, 0, 0, 0);
        acc1 = __builtin_amdgcn_mfma_f32_16x16x32_bf16(a, b1, acc1, 0, 0, 0);
    }

    // epilogue: C layout col=lm, row=4*q+r ; scale + fused bias/theta
    #pragma unroll
    for (int r = 0; r < 4; ++r) {
        int row = row0 + w * 16 + q * 4 + r;
        G[(size_t)row * GSTR + 0  + lm] = fmaf(acc0[r], INV2PI, bc[0]);
        G[(size_t)row * GSTR + 16 + lm] = fmaf(acc1[r], INV2PI, bc[1]);
    }
}

// ---------------------------------------------------------------------------
// Kernel 2: LSTM recurrence (r5-proven, verbatim). 32 lanes/row, 2 rows/wave.
// ---------------------------------------------------------------------------
__global__ __launch_bounds__(64)
void k2_lstm(const float* __restrict__ G,
             const float* __restrict__ Wf, const float* __restrict__ Wi,
             const float* __restrict__ Wu, const float* __restrict__ Wo,
             float* __restrict__ out)
{
    __shared__ float gs[SEQL * 64];       // 32 KB: [t][r*32 + g*8 + j]

    const int tid = threadIdx.x;          // 0..63, 1 wave
    const int l32 = tid & 31;
    const int g   = l32 >> 3;             // gate 0..3 (f,i,u,o)
    const int j   = l32 & 7;              // qubit
    const int r   = tid >> 5;             // row-in-block
    const int b   = blockIdx.x * 2 + r;

    // ---- bulk stage this block's G timeline (128 t x 2 rows x 32 f32) ----
    {
        const float* gsrc = G + (size_t)blockIdx.x * 64;
        #pragma unroll 4
        for (int i = 0; i < 32; ++i) {
            int sl = i * 64 + tid;        // float4 slot 0..2047
            int st = sl >> 4, pc = sl & 15;
            float4 v = *reinterpret_cast<const float4*>(
                gsrc + (size_t)st * (BATCHN * GSTR) + pc * 4);
            *reinterpret_cast<float4*>(&gs[sl * 4]) = v;
        }
    }
    __syncthreads();

    const float* Wsel = (g==0) ? Wf : (g==1) ? Wi : (g==2) ? Wu : Wo;

    // permuted, pre-scaled h-weights: dot = sum_r H[r]*Whp[r], H[r]=h[j^r]
    float Whp[8];
    #pragma unroll
    for (int rr = 0; rr < 8; ++rr)
        Whp[rr] = Wsel[j * DIN + EMBED + (j ^ rr)] * INV2PI;

    float H[8];
    #pragma unroll
    for (int rr = 0; rr < 8; ++rr) H[rr] = 0.f;
    float c_own = 0.f, h_own = 0.f;

    const float* gp = gs + tid;           // t*64 + r*32 + l32 == t*64 + tid
    float n = gp[0];

    const bool m1 = (j >= 1), m2 = (j >= 2), m4 = (j >= 4), jz = (j == 0);
    const bool isU = (g == 2);

    for (int t = 0; t < SEQL; ++t) {
        // prefetch next step's value from LDS (off the dependence chain)
        float nn = gp[((t + 1 < SEQL) ? t + 1 : t) * 64];

        // a (revolutions) = G + h-dot (split 2x4 chains)
        float sA = fmaf(H[0], Whp[0], fmaf(H[1], Whp[1],
                    fmaf(H[2], Whp[2], H[3] * Whp[3])));
        float sB = fmaf(H[4], Whp[4], fmaf(H[5], Whp[5],
                    fmaf(H[6], Whp[6], H[7] * Whp[7])));
        float cs = __builtin_amdgcn_cosf(n + sA + sB);

        // inclusive prefix product over qubit group (row_shr, guarded)
        float p = cs, s;
        s = updpf<DPP_SHR(1)>(1.0f, p); p *= (m1 ? s : 1.0f);
        s = updpf<DPP_SHR(2)>(1.0f, p); p *= (m2 ? s : 1.0f);
        s = updpf<DPP_SHR(4)>(1.0f, p); p *= (m4 ? s : 1.0f);
        // product of cs_1..cs_7 (butterfly; lane j=0 contributes 1)
        float v = jz ? 1.0f : cs;
        v *= updpf<DPP_QP(1,0,3,2)>(v, v);
        v *= updpf<DPP_QP(2,3,0,1)>(v, v);
        float xl = updpf<DPP_SHL(4)>(v, v);
        float xr = updpf<DPP_SHR(4)>(v, v);
        v *= (m4 ? xr : xl);
        float qv = jz ? v : p;

        // activation: u -> tanh(qv); f,i,o -> sigmoid(qv)=0.5+0.5*tanh(qv/2)
        float z  = isU ? qv : 0.5f * qv;
        float tt = tanh54(z);
        float act = isU ? tt : fmaf(0.5f, tt, 0.5f);

        // gather the 4 gate values for this qubit (parallel swizzles)
        float fv = swzf<0x0007>(act);     // lane & 7        -> gate f
        float iv = swzf<0x0107>(act);     // (lane&7)|8      -> gate i
        float uv = swzf<0x0207>(act);     // (lane&7)|16     -> gate u
        float ov = swzf<0x0307>(act);     // (lane&7)|24     -> gate o

        c_own = fmaf(fv, c_own, iv * uv); // |c| <= 2.07
        h_own = ov * tanh76(c_own);

        // all-gather h across the 8-lane qubit group: H[r] = h[j^r]
        H[0] = h_own;
        H[1] = updpf<DPP_QP(1,0,3,2)>(H[0], H[0]);
        H[2] = updpf<DPP_QP(2,3,0,1)>(H[0], H[0]);
        H[3] = updpf<DPP_QP(2,3,0,1)>(H[1], H[1]);
        #pragma unroll
        for (int rr = 0; rr < 4; ++rr) {
            float yl = updpf<DPP_SHL(4)>(H[rr], H[rr]);
            float yr = updpf<DPP_SHR(4)>(H[rr], H[rr]);
            H[4 + rr] = m4 ? yr : yl;
        }

        n = nn;
    }

    if (l32 < 8) out[b * NQ + j] = h_own;
}

// ---------------------------------------------------------------------------
extern "C" void kernel_launch(void* const* d_in, const int* in_sizes, int n_in,
                              void* d_out, int out_size, void* d_ws, size_t ws_size,
                              hipStream_t stream)
{
    const int*   sent = (const int*)  d_in[0];
    // d_in[1] = features : unused by the reference
    const float* emb  = (const float*)d_in[2];
    const float* Wf   = (const float*)d_in[3];
    const float* bf   = (const float*)d_in[4];
    const float* Wi   = (const float*)d_in[5];
    const float* bi   = (const float*)d_in[6];
    const float* Wu   = (const float*)d_in[7];
    const float* bu   = (const float*)d_in[8];
    const float* Wo   = (const float*)d_in[9];
    const float* bo   = (const float*)d_in[10];
    const float* thf  = (const float*)d_in[11];
    const float* thi  = (const float*)d_in[12];
    const float* thu  = (const float*)d_in[13];
    const float* tho  = (const float*)d_in[14];
    float* out = (float*)d_out;

    float* G = (float*)d_ws;   // 32768 * 32 * 4B = 4 MB

    k1_gates<<<NROWS/64, 256, 0, stream>>>(sent, emb, Wf, Wi, Wu, Wo,
                                           bf, bi, bu, bo,
                                           thf, thi, thu, tho, G);
    k2_lstm<<<BATCHN/2, 64, 0, stream>>>(G, Wf, Wi, Wu, Wo, out);
}

// Round 8
// 50.724 us; speedup vs baseline: 1.4888x; 1.0451x over previous
//
#include <hip/hip_runtime.h>
#include <hip/hip_bf16.h>

#define NQ     8
#define SEQL   128
#define BATCHN 256
#define EMBED  512
#define DIN    520          // EMBED + NQ
#define NROWS  (SEQL*BATCHN) // 32768
#define GSTR   32           // 4 gates * 8 qubits
#define INV2PI 0.15915494309189535f
#define WROW   524          // Wlds padded row (shorts): 262 words = 6 banks offset

typedef __attribute__((ext_vector_type(8))) short  bf16x8;
typedef __attribute__((ext_vector_type(4))) float  f32x4;
typedef unsigned int uint2v __attribute__((ext_vector_type(2)));

__device__ __forceinline__ short f2bf(float f) {
    union { __hip_bfloat16 h; short s; } u;
    u.h = __float2bfloat16(f);          // RNE convert
    return u.s;
}

// ---------------------------------------------------------------------------
// DPP helpers: row_shr:N -> lane i gets i-N ; row_shl:N -> i+N ;
//              row_ror:8 -> lane i gets i^8 within its 16-lane row
// ---------------------------------------------------------------------------
#define DPP_QP(a,b,c,d) ((a)|((b)<<2)|((c)<<4)|((d)<<6))
#define DPP_SHL(n) (0x100+(n))
#define DPP_SHR(n) (0x110+(n))
#define DPP_ROR(n) (0x120+(n))

template<int CTRL>
__device__ __forceinline__ float updpf(float old_, float src) {
    return __int_as_float(__builtin_amdgcn_update_dpp(
        __float_as_int(old_), __float_as_int(src), CTRL, 0xF, 0xF, false));
}

// value at lane^16: permlane16_swap returns {vdst,vsrc}; with both = x the
// pair holds {x[lane], x[lane^16]} in some order -> a^b^x extracts partner.
__device__ __forceinline__ float xor16f(float x) {
    unsigned xu = (unsigned)__float_as_int(x);
    uint2v r = __builtin_amdgcn_permlane16_swap(xu, xu, false, false);
    return __int_as_float((int)(r.x ^ r.y ^ xu));
}

__device__ __forceinline__ float frcp(float x) { return __builtin_amdgcn_rcpf(x); }
__device__ __forceinline__ float fexp2(float x) { return __builtin_amdgcn_exp2f(x); }

#define LOG2E  1.4426950408889634f
#define LOG2E2 2.8853900817779268f

// ---------------------------------------------------------------------------
// Kernel 1 (MFMA): G[row*32+c] = (emb[sent[row]].W_c + b_c + th_c) * INV2PI
//   256 thr = 4 waves, M=64 rows/block, N=32, K=512 in 16 steps of 32.
//   W staged ONCE to bf16 LDS (shared by all 4 waves; pad 524 -> b128 reads
//   land on distinct banks). A-fragments load DIRECTLY from emb (no reuse ->
//   no staging): per wave/iter = 16 rows x 128 B contiguous. No loop barriers.
//   Fragment pattern identical to r7 (proven): 8 consecutive bf16 per lane
//   from row-major [row][k]; C: col=lane&15, row=4*(lane>>4)+reg.
// ---------------------------------------------------------------------------
__global__ __launch_bounds__(256)
void k1_gates(const int* __restrict__ sent, const float* __restrict__ emb,
              const float* __restrict__ Wf, const float* __restrict__ Wi,
              const float* __restrict__ Wu, const float* __restrict__ Wo,
              const float* __restrict__ bf, const float* __restrict__ bi,
              const float* __restrict__ bu, const float* __restrict__ bo,
              const float* __restrict__ thf, const float* __restrict__ thi,
              const float* __restrict__ thu, const float* __restrict__ tho,
              float* __restrict__ G)
{
    __shared__ short Wlds[32][WROW];     // 33.5 KB bf16, [c][k]

    const int tid  = threadIdx.x;
    const int row0 = blockIdx.x * 64;

    // ---- stage W -> bf16 LDS: c = tid&31, segment = tid>>5 (64 floats) ----
    {
        const int c = tid & 31, seg = tid >> 5;
        const int g = c >> 3, j = c & 7;
        const float* W = (g==0) ? Wf : (g==1) ? Wi : (g==2) ? Wu : Wo;
        const float* src = W + (size_t)j * DIN + seg * 64;
        #pragma unroll
        for (int p = 0; p < 8; ++p) {
            float4 u = *reinterpret_cast<const float4*>(src + p * 8);
            float4 v = *reinterpret_cast<const float4*>(src + p * 8 + 4);
            bf16x8 pk;
            pk[0]=f2bf(u.x); pk[1]=f2bf(u.y); pk[2]=f2bf(u.z); pk[3]=f2bf(u.w);
            pk[4]=f2bf(v.x); pk[5]=f2bf(v.y); pk[6]=f2bf(v.z); pk[7]=f2bf(v.w);
            *reinterpret_cast<bf16x8*>(&Wlds[c][seg * 64 + p * 8]) = pk;
        }
    }

    const int l  = tid & 63;             // lane
    const int w  = tid >> 6;             // wave -> M-tile
    const int lm = l & 15;               // row-in-tile / col-in-tile
    const int q  = l >> 4;               // k-quarter (8 elems)

    const int    mytok = sent[row0 + w * 16 + lm];
    const float* arow  = emb + (size_t)mytok * EMBED;

    // bias/theta for the two N-tiles (c = n*16 + lm)
    float bc[2];
    #pragma unroll
    for (int n = 0; n < 2; ++n) {
        int c = n * 16 + lm;
        int g = c >> 3, j = c & 7;
        const float* B  = (g==0) ? bf  : (g==1) ? bi  : (g==2) ? bu  : bo;
        const float* Th = (g==0) ? thf : (g==1) ? thi : (g==2) ? thu : tho;
        bc[n] = (B[j] + Th[j]) * INV2PI;
    }
    __syncthreads();

    f32x4 acc0 = {0.f,0.f,0.f,0.f};
    f32x4 acc1 = {0.f,0.f,0.f,0.f};

    #pragma unroll
    for (int kc = 0; kc < 16; ++kc) {
        const int kl = kc * 32 + q * 8;
        float4 u = *reinterpret_cast<const float4*>(arow + kl);
        float4 v = *reinterpret_cast<const float4*>(arow + kl + 4);
        bf16x8 a;
        a[0]=f2bf(u.x); a[1]=f2bf(u.y); a[2]=f2bf(u.z); a[3]=f2bf(u.w);
        a[4]=f2bf(v.x); a[5]=f2bf(v.y); a[6]=f2bf(v.z); a[7]=f2bf(v.w);
        bf16x8 b0 = *reinterpret_cast<const bf16x8*>(&Wlds[lm][kl]);
        bf16x8 b1 = *reinterpret_cast<const bf16x8*>(&Wlds[16 + lm][kl]);
        acc0 = __builtin_amdgcn_mfma_f32_16x16x32_bf16(a, b0, acc0, 0, 0, 0);
        acc1 = __builtin_amdgcn_mfma_f32_16x16x32_bf16(a, b1, acc1, 0, 0, 0);
    }

    // epilogue: C layout col=lm, row=4*q+r ; scale + fused bias/theta
    #pragma unroll
    for (int r = 0; r < 4; ++r) {
        int row = row0 + w * 16 + q * 4 + r;
        G[(size_t)row * GSTR + 0  + lm] = fmaf(acc0[r], INV2PI, bc[0]);
        G[(size_t)row * GSTR + 16 + lm] = fmaf(acc1[r], INV2PI, bc[1]);
    }
}

// ---------------------------------------------------------------------------
// Kernel 2: LSTM recurrence, closed-form qlayer. 32 lanes/row, 2 rows/wave.
//   lane32 = g*8+j (gate bits at lane bits 3,4). All cross-lane on VALU:
//   j-group scan/butterfly/H-gather = DPP; gate gather = ror8 (^8),
//   permlane16_swap (^16), ror8 of that (^24) + cndmask selects.
//   Activations via exp2+rcp (shorter chain than Pade, more accurate).
// ---------------------------------------------------------------------------
__global__ __launch_bounds__(64)
void k2_lstm(const float* __restrict__ G,
             const float* __restrict__ Wf, const float* __restrict__ Wi,
             const float* __restrict__ Wu, const float* __restrict__ Wo,
             float* __restrict__ out)
{
    __shared__ float gs[SEQL * 64];       // 32 KB: [t][r*32 + g*8 + j]

    const int tid = threadIdx.x;          // 0..63, 1 wave
    const int l32 = tid & 31;
    const int g   = l32 >> 3;             // gate 0..3 (f,i,u,o)
    const int j   = l32 & 7;              // qubit
    const int r   = tid >> 5;             // row-in-block
    const int b   = blockIdx.x * 2 + r;

    // ---- bulk stage this block's G timeline (128 t x 2 rows x 32 f32) ----
    {
        const float* gsrc = G + (size_t)blockIdx.x * 64;
        #pragma unroll 4
        for (int i = 0; i < 32; ++i) {
            int sl = i * 64 + tid;        // float4 slot 0..2047
            int st = sl >> 4, pc = sl & 15;
            float4 v = *reinterpret_cast<const float4*>(
                gsrc + (size_t)st * (BATCHN * GSTR) + pc * 4);
            *reinterpret_cast<float4*>(&gs[sl * 4]) = v;
        }
    }
    __syncthreads();

    const float* Wsel = (g==0) ? Wf : (g==1) ? Wi : (g==2) ? Wu : Wo;

    // permuted, pre-scaled h-weights: dot = sum_r H[r]*Whp[r], H[r]=h[j^r]
    float Whp[8];
    #pragma unroll
    for (int rr = 0; rr < 8; ++rr)
        Whp[rr] = Wsel[j * DIN + EMBED + (j ^ rr)] * INV2PI;

    float H[8];
    #pragma unroll
    for (int rr = 0; rr < 8; ++rr) H[rr] = 0.f;
    float c_own = 0.f, h_own = 0.f;

    const float* gp = gs + tid;           // t*64 + r*32 + l32 == t*64 + tid
    float n = gp[0];

    const bool m1 = (j >= 1), m2 = (j >= 2), m4 = (j >= 4), jz = (j == 0);
    // activation constants: u -> tanh; f,i,o -> sigmoid
    //   sigmoid(x) = rcp(1 + 2^(-LOG2E*x));  tanh(x) = 1 - 2*rcp(1 + 2^(LOG2E2*x))
    const bool isU = (g == 2);
    const float ek = isU ? LOG2E2 : -LOG2E;
    const float sk = isU ? -2.0f  : 1.0f;
    const float ok = isU ? 1.0f   : 0.0f;

    for (int t = 0; t < SEQL; ++t) {
        // prefetch next step's value from LDS (off the dependence chain)
        float nn = gp[((t + 1 < SEQL) ? t + 1 : t) * 64];

        // a (revolutions) = G + h-dot (split 2x4 chains)
        float sA = fmaf(H[0], Whp[0], fmaf(H[1], Whp[1],
                    fmaf(H[2], Whp[2], H[3] * Whp[3])));
        float sB = fmaf(H[4], Whp[4], fmaf(H[5], Whp[5],
                    fmaf(H[6], Whp[6], H[7] * Whp[7])));
        float cs = __builtin_amdgcn_cosf(n + sA + sB);

        // inclusive prefix product over qubit group (row_shr, guarded)
        float p = cs, s;
        s = updpf<DPP_SHR(1)>(1.0f, p); p *= (m1 ? s : 1.0f);
        s = updpf<DPP_SHR(2)>(1.0f, p); p *= (m2 ? s : 1.0f);
        s = updpf<DPP_SHR(4)>(1.0f, p); p *= (m4 ? s : 1.0f);
        // product of cs_1..cs_7 (butterfly; lane j=0 contributes 1)
        float v = jz ? 1.0f : cs;
        v *= updpf<DPP_QP(1,0,3,2)>(v, v);
        v *= updpf<DPP_QP(2,3,0,1)>(v, v);
        float xl = updpf<DPP_SHL(4)>(v, v);
        float xr = updpf<DPP_SHR(4)>(v, v);
        v *= (m4 ? xr : xl);
        float qv = jz ? v : p;

        // activation (branchless, exp2+rcp)
        float act = fmaf(sk, frcp(1.0f + fexp2(ek * qv)), ok);

        // gate gather, all-VALU: lane^8 = ror8, lane^16 = permlane16_swap,
        // lane^24 = ror8 of that. Gate bits = lane bits 3,4.
        float A   = act;
        float B8  = updpf<DPP_ROR(8)>(A, A);
        float C16 = xor16f(A);
        float D24 = updpf<DPP_ROR(8)>(C16, C16);
        float fv = (g==0) ? A : (g==1) ? B8 : (g==2) ? C16 : D24;
        float iv = (g==1) ? A : (g==0) ? B8 : (g==3) ? C16 : D24;
        float uv = (g==2) ? A : (g==3) ? B8 : (g==0) ? C16 : D24;
        float ov = (g==3) ? A : (g==2) ? B8 : (g==1) ? C16 : D24;

        c_own = fmaf(fv, c_own, iv * uv); // |c| <= 2.07
        float tc = fmaf(-2.0f, frcp(1.0f + fexp2(LOG2E2 * c_own)), 1.0f);
        h_own = ov * tc;

        // all-gather h across the 8-lane qubit group: H[r] = h[j^r]
        H[0] = h_own;
        H[1] = updpf<DPP_QP(1,0,3,2)>(H[0], H[0]);
        H[2] = updpf<DPP_QP(2,3,0,1)>(H[0], H[0]);
        H[3] = updpf<DPP_QP(2,3,0,1)>(H[1], H[1]);
        #pragma unroll
        for (int rr = 0; rr < 4; ++rr) {
            float yl = updpf<DPP_SHL(4)>(H[rr], H[rr]);
            float yr = updpf<DPP_SHR(4)>(H[rr], H[rr]);
            H[4 + rr] = m4 ? yr : yl;
        }

        n = nn;
    }

    if (l32 < 8) out[b * NQ + j] = h_own;
}

// ---------------------------------------------------------------------------
extern "C" void kernel_launch(void* const* d_in, const int* in_sizes, int n_in,
                              void* d_out, int out_size, void* d_ws, size_t ws_size,
                              hipStream_t stream)
{
    const int*   sent = (const int*)  d_in[0];
    // d_in[1] = features : unused by the reference
    const float* emb  = (const float*)d_in[2];
    const float* Wf   = (const float*)d_in[3];
    const float* bf   = (const float*)d_in[4];
    const float* Wi   = (const float*)d_in[5];
    const float* bi   = (const float*)d_in[6];
    const float* Wu   = (const float*)d_in[7];
    const float* bu   = (const float*)d_in[8];
    const float* Wo   = (const float*)d_in[9];
    const float* bo   = (const float*)d_in[10];
    const float* thf  = (const float*)d_in[11];
    const float* thi  = (const float*)d_in[12];
    const float* thu  = (const float*)d_in[13];
    const float* tho  = (const float*)d_in[14];
    float* out = (float*)d_out;

    float* G = (float*)d_ws;   // 32768 * 32 * 4B = 4 MB

    k1_gates<<<NROWS/64, 256, 0, stream>>>(sent, emb, Wf, Wi, Wu, Wo,
                                           bf, bi, bu, bo,
                                           thf, thi, thu, tho, G);
    k2_lstm<<<BATCHN/2, 64, 0, stream>>>(G, Wf, Wi, Wu, Wo, out);
}